// Round 4
// baseline (172.736 us; speedup 1.0000x reference)
//
#include <hip/hip_runtime.h>
#include <math.h>

// Problem constants (fixed by the reference)
#define NQ   1024      // B*LT
#define DIM  512
#define NH   8
#define DHD  64
#define DFF  2048
#define LM   64        // LMEM

typedef __bf16 bf16x8 __attribute__((ext_vector_type(8)));
typedef float  f32x4  __attribute__((ext_vector_type(4)));

__device__ __forceinline__ unsigned short f2bf(float f) {
    unsigned u = __builtin_bit_cast(unsigned, f);
    return (unsigned short)((u + 0x7fffu + ((u >> 16) & 1u)) >> 16);
}
__device__ __forceinline__ float bflo(unsigned p) {
    return __builtin_bit_cast(float, p << 16);
}
__device__ __forceinline__ float bfhi(unsigned p) {
    return __builtin_bit_cast(float, p & 0xffff0000u);
}

__device__ __forceinline__ void gload16(const void* g, void* l) {
    __builtin_amdgcn_global_load_lds(
        (const __attribute__((address_space(1))) unsigned*)g,
        (__attribute__((address_space(3))) unsigned*)l, 16, 0, 0);
}

// ---------------------------------------------------------------- helpers
__device__ __forceinline__ float blk_sum(float v, volatile float* red) {
#pragma unroll
    for (int o = 32; o; o >>= 1) v += __shfl_down(v, o);
    __syncthreads();
    if ((threadIdx.x & 63) == 0) red[threadIdx.x >> 6] = v;
    __syncthreads();
    return red[0] + red[1] + red[2] + red[3];
}

// ------------------------------------------------- K1: LN(dec_output) + argmax
__global__ __launch_bounds__(256) void ln0_argmax_k(
    const float* __restrict__ dec_out, const float* __restrict__ attn_out,
    const float* __restrict__ g, const float* __restrict__ be,
    float* __restrict__ x, unsigned* __restrict__ xb, int* __restrict__ samples)
{
    __shared__ float red[4];
    __shared__ float rv[4]; __shared__ int ri[4];
    const int n = blockIdx.x, t = threadIdx.x;

    float2 v = ((const float2*)(dec_out + (size_t)n * DIM))[t];
    float mu  = blk_sum(v.x + v.y, red) * (1.f / DIM);
    float dx = v.x - mu, dy = v.y - mu;
    float var = blk_sum(dx * dx + dy * dy, red) * (1.f / DIM);
    float rs = rsqrtf(var + 1e-5f);
    float2 gg = ((const float2*)g)[t], bb = ((const float2*)be)[t];
    float ox = dx * rs * gg.x + bb.x, oy = dy * rs * gg.y + bb.y;
    ((float2*)(x + (size_t)n * DIM))[t] = make_float2(ox, oy);
    xb[(size_t)n * 256 + t] = (unsigned)f2bf(ox) | ((unsigned)f2bf(oy) << 16);

    const float* ar = attn_out + (size_t)n * 1025;
    float bv = -INFINITY; int bi = 0x7fffffff;
    for (int i = t; i < 1025; i += 256) {
        float val = ar[i];
        if (val > bv || (val == bv && i < bi)) { bv = val; bi = i; }
    }
#pragma unroll
    for (int o = 32; o; o >>= 1) {
        float ov = __shfl_down(bv, o); int oi = __shfl_down(bi, o);
        if (ov > bv || (ov == bv && oi < bi)) { bv = ov; bi = oi; }
    }
    if ((t & 63) == 0) { rv[t >> 6] = bv; ri[t >> 6] = bi; }
    __syncthreads();
    if (t == 0) {
#pragma unroll
        for (int w = 1; w < 4; ++w)
            if (rv[w] > bv || (rv[w] == bv && ri[w] < bi)) { bv = rv[w]; bi = ri[w]; }
        samples[n] = bi - 1;
    }
}

// ------------------------------------------------- weight prep: fp32 -> bf16 (+T)
struct PrepPtrs {
    const float* src[8];
    unsigned short* dst[8];
};
__global__ __launch_bounds__(256) void prep_weights_k(PrepPtrs p) {
    __shared__ float tile[32][33];
    const int bid = blockIdx.x;
    int m, lt;
    if (bid < 1024) { m = bid >> 8; lt = bid & 255; }
    else { m = 4 + ((bid - 1024) >> 10); lt = (bid - 1024) & 1023; }
    const int RS = (m < 4) ? 512 : ((m == 5 || m == 7) ? 2048 : 512);
    const int CS = (m < 4) ? 512 : ((m == 5 || m == 7) ? 512 : 2048);
    const int TC = CS >> 5;
    const int tr = lt / TC, tc = lt % TC;
    const float* s = p.src[m];
    unsigned short* d = p.dst[m];
    const int tx = threadIdx.x & 31, ty = threadIdx.x >> 5;
    if (m == 1) {
#pragma unroll
        for (int i = 0; i < 32; i += 8) {
            size_t idx = (size_t)(tr * 32 + ty + i) * CS + tc * 32 + tx;
            d[idx] = f2bf(s[idx]);
        }
    } else {
#pragma unroll
        for (int i = 0; i < 32; i += 8)
            tile[ty + i][tx] = s[(size_t)(tr * 32 + ty + i) * CS + tc * 32 + tx];
        __syncthreads();
#pragma unroll
        for (int i = 0; i < 32; i += 8)
            d[(size_t)(tc * 32 + ty + i) * RS + tr * 32 + tx] = f2bf(tile[tx][ty + i]);
    }
}

// ------------------------------------------------- bf16 MFMA GEMM, 64x64 tile
template<bool RELU, bool BIAS, bool RES, bool WF32, bool WBF>
__global__ __launch_bounds__(256) void mfma_gemm(
    const unsigned short* __restrict__ A, const unsigned short* __restrict__ Bt,
    float* __restrict__ Cf, unsigned short* __restrict__ Cb,
    const float* __restrict__ bias, const float* __restrict__ res,
    int K, int lda, int ldb, int ldc,
    int sA, int sB, int sC, int sBias)
{
    __shared__ unsigned short Ab[2][64 * 64];
    __shared__ unsigned short Bb[2][64 * 64];
    const int t = threadIdx.x, lane = t & 63, wid = t >> 6;
    const int bm = blockIdx.y * 64, bn = blockIdx.x * 64, bz = blockIdx.z;
    const unsigned short* Abase = A + (size_t)bz * sA + (size_t)bm * lda;
    const unsigned short* Bbase = Bt + (size_t)bz * sB + (size_t)bn * ldb;

    const int r0 = wid * 16 + (lane >> 3);
    const int cbs = lane & 7;

#define STAGE_T(buf, base, ld, kt)                                              \
    {                                                                           \
        int r_ = r0;                                                            \
        gload16(base + (size_t)r_ * ld + (kt) * 64 + ((cbs ^ (r_ & 7)) << 3),   \
                &buf[(wid * 2 + 0) * 512]);                                     \
        r_ = r0 + 8;                                                            \
        gload16(base + (size_t)r_ * ld + (kt) * 64 + ((cbs ^ (r_ & 7)) << 3),   \
                &buf[(wid * 2 + 1) * 512]);                                     \
    }

    const int lr = lane & 15, lg = lane >> 4;
    const int wr = (wid >> 1) * 32, wc = (wid & 1) * 32;
    const int mA0 = wr + lr, mA1 = wr + 16 + lr;
    const int nB0 = wc + lr, nB1 = wc + 16 + lr;
    f32x4 acc[2][2] = {};

#define COMPUTE(b)                                                              \
    _Pragma("unroll")                                                           \
    for (int kk = 0; kk < 2; ++kk) {                                            \
        const int kb = kk * 4 + lg;                                             \
        bf16x8 a0 = *(const bf16x8*)&Ab[b][mA0 * 64 + ((kb ^ (mA0 & 7)) << 3)]; \
        bf16x8 a1 = *(const bf16x8*)&Ab[b][mA1 * 64 + ((kb ^ (mA1 & 7)) << 3)]; \
        bf16x8 b0 = *(const bf16x8*)&Bb[b][nB0 * 64 + ((kb ^ (nB0 & 7)) << 3)]; \
        bf16x8 b1 = *(const bf16x8*)&Bb[b][nB1 * 64 + ((kb ^ (nB1 & 7)) << 3)]; \
        acc[0][0] = __builtin_amdgcn_mfma_f32_16x16x32_bf16(a0, b0, acc[0][0], 0, 0, 0); \
        acc[0][1] = __builtin_amdgcn_mfma_f32_16x16x32_bf16(a0, b1, acc[0][1], 0, 0, 0); \
        acc[1][0] = __builtin_amdgcn_mfma_f32_16x16x32_bf16(a1, b0, acc[1][0], 0, 0, 0); \
        acc[1][1] = __builtin_amdgcn_mfma_f32_16x16x32_bf16(a1, b1, acc[1][1], 0, 0, 0); \
    }

    STAGE_T(Ab[0], Abase, lda, 0);
    STAGE_T(Bb[0], Bbase, ldb, 0);
    __syncthreads();
    const int NT = K >> 6;
    int cur = 0;
    for (int kt = 0; kt < NT; ++kt) {
        if (kt + 1 < NT) {
            STAGE_T(Ab[cur ^ 1], Abase, lda, kt + 1);
            STAGE_T(Bb[cur ^ 1], Bbase, ldb, kt + 1);
        }
        if (cur == 0) { COMPUTE(0); } else { COMPUTE(1); }
        __syncthreads();
        cur ^= 1;
    }

#pragma unroll
    for (int fm = 0; fm < 2; ++fm)
#pragma unroll
    for (int fn = 0; fn < 2; ++fn) {
        const int col = bn + wc + fn * 16 + lr;
        float bia = BIAS ? bias[bz * sBias + col] : 0.f;
#pragma unroll
        for (int r = 0; r < 4; ++r) {
            const int row = bm + wr + fm * 16 + lg * 4 + r;
            const size_t ci = (size_t)bz * sC + (size_t)row * ldc + col;
            float v = acc[fm][fn][r] + bia;
            if (RES) v += res[(size_t)row * ldc + col];
            if (RELU) v = fmaxf(v, 0.f);
            if (WF32) Cf[ci] = v;
            if (WBF)  Cb[ci] = f2bf(v);
        }
    }
#undef STAGE_T
#undef COMPUTE
}

// ------------------------------------------------- bf16 MFMA GEMM, 128x128 tile
// C[bm..+128, bn..+128] = A @ Bt^T (+bias) (relu), bf16 out only.
template<bool RELU>
__global__ __launch_bounds__(256) void mfma_gemm128(
    const unsigned short* __restrict__ A, const unsigned short* __restrict__ Bt,
    unsigned short* __restrict__ Cb, const float* __restrict__ bias,
    int K, int lda, int ldb, int ldc)
{
    __shared__ unsigned short Ab[2][128 * 64];
    __shared__ unsigned short Bb[2][128 * 64];
    const int t = threadIdx.x, lane = t & 63, wid = t >> 6;
    const int bn = blockIdx.x * 128, bm = blockIdx.y * 128;
    const unsigned short* Abase = A + (size_t)bm * lda;
    const unsigned short* Bbase = Bt + (size_t)bn * ldb;

    const int srow = lane >> 3;    // 0..7
    const int c8 = lane & 7;

#define STAGE128(buf, base, ld, kt)                                             \
    _Pragma("unroll")                                                           \
    for (int i = 0; i < 4; ++i) {                                               \
        int row = i * 32 + wid * 8 + srow;                                      \
        gload16(base + (size_t)row * ld + (kt) * 64 + ((c8 ^ (row & 7)) << 3),  \
                &buf[(i * 32 + wid * 8) * 64]);                                 \
    }

    const int lr = lane & 15, lg = lane >> 4;
    const int wr = (wid >> 1) * 64, wc = (wid & 1) * 64;
    f32x4 acc[4][4] = {};

#define COMPUTE128(b)                                                           \
    _Pragma("unroll")                                                           \
    for (int kk = 0; kk < 2; ++kk) {                                            \
        const int kb = kk * 4 + lg;                                             \
        bf16x8 af[4], bfv[4];                                                   \
        _Pragma("unroll")                                                       \
        for (int fm = 0; fm < 4; ++fm) {                                        \
            int row = wr + fm * 16 + lr;                                        \
            af[fm] = *(const bf16x8*)&Ab[b][row * 64 + ((kb ^ (row & 7)) << 3)];\
        }                                                                       \
        _Pragma("unroll")                                                       \
        for (int fn = 0; fn < 4; ++fn) {                                        \
            int col = wc + fn * 16 + lr;                                        \
            bfv[fn] = *(const bf16x8*)&Bb[b][col * 64 + ((kb ^ (col & 7)) << 3)];\
        }                                                                       \
        _Pragma("unroll")                                                       \
        for (int fm = 0; fm < 4; ++fm)                                          \
            _Pragma("unroll")                                                   \
            for (int fn = 0; fn < 4; ++fn)                                      \
                acc[fm][fn] = __builtin_amdgcn_mfma_f32_16x16x32_bf16(          \
                    af[fm], bfv[fn], acc[fm][fn], 0, 0, 0);                     \
    }

    STAGE128(Ab[0], Abase, lda, 0);
    STAGE128(Bb[0], Bbase, ldb, 0);
    __syncthreads();
    const int NT = K >> 6;
    int cur = 0;
    for (int kt = 0; kt < NT; ++kt) {
        if (kt + 1 < NT) {
            STAGE128(Ab[cur ^ 1], Abase, lda, kt + 1);
            STAGE128(Bb[cur ^ 1], Bbase, ldb, kt + 1);
        }
        if (cur == 0) { COMPUTE128(0); } else { COMPUTE128(1); }
        __syncthreads();
        cur ^= 1;
    }

#pragma unroll
    for (int fn = 0; fn < 4; ++fn) {
        const int col = bn + wc + fn * 16 + lr;
        const float bia = bias[col];
#pragma unroll
        for (int fm = 0; fm < 4; ++fm) {
#pragma unroll
            for (int r = 0; r < 4; ++r) {
                const int row = bm + wr + fm * 16 + lg * 4 + r;
                float v = acc[fm][fn][r] + bia;
                if (RELU) v = fmaxf(v, 0.f);
                Cb[(size_t)row * ldc + col] = f2bf(v);
            }
        }
    }
#undef STAGE128
#undef COMPUTE128
}

// ------------------------------------------------- K5a: scores(MFMA) -> softmax -> P
// scores[k,h] = enc[s,k,:]·u[n,h,:] + qh[n]·bk_h ; P bf16 [n][k][h] to global.
__global__ __launch_bounds__(256) void attn_scores_k(
    const float* __restrict__ qh, const unsigned short* __restrict__ u_bf,
    const float* __restrict__ enc, const int* __restrict__ maskmem,
    const int* __restrict__ samples, const float* __restrict__ bk,
    unsigned short* __restrict__ p_out)
{
    __shared__ float S_lds[8 * 68];
    __shared__ float Cs_lds[8];
    __shared__ int Msk_lds[64];

    const int n = blockIdx.x, t = threadIdx.x;
    const int lane = t & 63, w = t >> 6;
    int s = samples[n]; if (s < 0) s = 0;

    // issue K-loads first (they cover the mask/Cs work + L1 warmup)
    const float4* kb = (const float4*)(enc + (size_t)s * (LM * DIM));
    const int key = w * 16 + (lane & 15);
    const int lg = lane >> 4;
    const int h = lane & 15;
    const int base = key * 128 + lg * 2;  // float4 units
    float4 pf[4][2];
#pragma unroll
    for (int ss = 0; ss < 4; ++ss) {
        pf[ss][0] = kb[base + ss * 8];
        pf[ss][1] = kb[base + ss * 8 + 1];
    }

    if (w == 0) Msk_lds[lane] = maskmem[(size_t)s * LM + lane];
    if (w == 1) {
        int hq = lane >> 3, j = lane & 7;
        const float4* q4 = (const float4*)(qh + (size_t)n * DIM + hq * 64 + j * 8);
        const float4* b4 = (const float4*)(bk + hq * 64 + j * 8);
        float4 qa = q4[0], qb = q4[1], ba = b4[0], bb = b4[1];
        float c = qa.x * ba.x + qa.y * ba.y + qa.z * ba.z + qa.w * ba.w
                + qb.x * bb.x + qb.y * bb.y + qb.z * bb.z + qb.w * bb.w;
        c += __shfl_xor(c, 1); c += __shfl_xor(c, 2); c += __shfl_xor(c, 4);
        if (j == 0) Cs_lds[hq] = c;
    }

    // scores via MFMA; B-fragment (u) read straight from global (L1-resident 8 KB)
    const unsigned short* ub = u_bf + (size_t)n * 4096 + (size_t)(h & 7) * 512;
    f32x4 acc = {};
#pragma unroll
    for (int step = 0; step < 16; ++step) {
        float4 a0 = pf[step & 3][0], a1 = pf[step & 3][1];
        if (step + 4 < 16) {
            pf[step & 3][0] = kb[base + (step + 4) * 8];
            pf[step & 3][1] = kb[base + (step + 4) * 8 + 1];
        }
        bf16x8 af;
        af[0] = (__bf16)a0.x; af[1] = (__bf16)a0.y;
        af[2] = (__bf16)a0.z; af[3] = (__bf16)a0.w;
        af[4] = (__bf16)a1.x; af[5] = (__bf16)a1.y;
        af[6] = (__bf16)a1.z; af[7] = (__bf16)a1.w;
        bf16x8 bfr = *(const bf16x8*)&ub[(step * 4 + lg) * 8];
        acc = __builtin_amdgcn_mfma_f32_16x16x32_bf16(af, bfr, acc, 0, 0, 0);
    }
    if (h < 8) {
#pragma unroll
        for (int r = 0; r < 4; ++r)
            S_lds[h * 68 + w * 16 + lg * 4 + r] = acc[r];
    }
    __syncthreads();

    // wave-parallel softmax (wave w handles heads w, w+4); write P to global
    unsigned short* pg = p_out + (size_t)n * 512 + lane * 8;
#pragma unroll
    for (int hh = 0; hh < 2; ++hh) {
        const int h2 = w + hh * 4;
        float sc = (S_lds[h2 * 68 + lane] + Cs_lds[h2]) * 0.125f;
        sc = (Msk_lds[lane] != 0) ? sc : -1e9f;
        float m = sc;
#pragma unroll
        for (int o = 32; o; o >>= 1) m = fmaxf(m, __shfl_xor(m, o));
        float e = __expf(sc - m);
        float su = e;
#pragma unroll
        for (int o = 32; o; o >>= 1) su += __shfl_xor(su, o);
        pg[h2] = f2bf(e / su);
    }
}

// ------------------------------------------------- K5b: PV (d-halved, k-split)
__global__ __launch_bounds__(256) void attn_pv_k(
    const unsigned short* __restrict__ p_in, const float* __restrict__ vemb,
    const int* __restrict__ samples, unsigned* __restrict__ a_bf)
{
    __shared__ uint4 P_lds[64];
    __shared__ float2 Red[8][128];
    const int n = blockIdx.x, dh = blockIdx.y, t = threadIdx.x;
    int s = samples[n]; if (s < 0) s = 0;

    if (t < 64) P_lds[t] = ((const uint4*)(p_in + (size_t)n * 512))[t];
    __syncthreads();

    const int c = t & 127, kh = t >> 7;
    const float2* vb = (const float2*)(vemb + (size_t)s * (LM * DIM)) + dh * 128 + c;
    float2 acc8[8];
#pragma unroll
    for (int hh = 0; hh < 8; ++hh) acc8[hh] = make_float2(0.f, 0.f);
#pragma unroll 8
    for (int i = 0; i < 32; ++i) {
        const int k = kh * 32 + i;
        float2 v = vb[(size_t)k * 256];
        uint4 pr = P_lds[k];
        float p0 = bflo(pr.x), p1 = bfhi(pr.x);
        float p2 = bflo(pr.y), p3 = bfhi(pr.y);
        float p4 = bflo(pr.z), p5 = bfhi(pr.z);
        float p6 = bflo(pr.w), p7 = bfhi(pr.w);
        acc8[0].x = fmaf(p0, v.x, acc8[0].x); acc8[0].y = fmaf(p0, v.y, acc8[0].y);
        acc8[1].x = fmaf(p1, v.x, acc8[1].x); acc8[1].y = fmaf(p1, v.y, acc8[1].y);
        acc8[2].x = fmaf(p2, v.x, acc8[2].x); acc8[2].y = fmaf(p2, v.y, acc8[2].y);
        acc8[3].x = fmaf(p3, v.x, acc8[3].x); acc8[3].y = fmaf(p3, v.y, acc8[3].y);
        acc8[4].x = fmaf(p4, v.x, acc8[4].x); acc8[4].y = fmaf(p4, v.y, acc8[4].y);
        acc8[5].x = fmaf(p5, v.x, acc8[5].x); acc8[5].y = fmaf(p5, v.y, acc8[5].y);
        acc8[6].x = fmaf(p6, v.x, acc8[6].x); acc8[6].y = fmaf(p6, v.y, acc8[6].y);
        acc8[7].x = fmaf(p7, v.x, acc8[7].x); acc8[7].y = fmaf(p7, v.y, acc8[7].y);
    }
    if (kh == 1) {
#pragma unroll
        for (int hh = 0; hh < 8; ++hh) Red[hh][c] = acc8[hh];
    }
    __syncthreads();
    if (kh == 0) {
        unsigned* an = a_bf + (size_t)n * 2048 + dh * 128;
#pragma unroll
        for (int hh = 0; hh < 8; ++hh) {
            float2 r = Red[hh][c];
            float ox = acc8[hh].x + r.x, oy = acc8[hh].y + r.y;
            an[hh * 256 + c] = (unsigned)f2bf(ox) | ((unsigned)f2bf(oy) << 16);
        }
    }
}

// ------------------------------------------------- K10: LN(t1) mask + x residual
__global__ __launch_bounds__(256) void ln1_mask_add_k(
    const float* __restrict__ t1, const float* __restrict__ g,
    const float* __restrict__ be, const int* __restrict__ samples,
    const float* __restrict__ x, float* __restrict__ dec, unsigned* __restrict__ decb)
{
    __shared__ float red[4];
    const int n = blockIdx.x, t = threadIdx.x;
    float2 v = ((const float2*)(t1 + (size_t)n * DIM))[t];
    float mu  = blk_sum(v.x + v.y, red) * (1.f / DIM);
    float dx = v.x - mu, dy = v.y - mu;
    float var = blk_sum(dx * dx + dy * dy, red) * (1.f / DIM);
    float rs = rsqrtf(var + 1e-5f);
    float2 gg = ((const float2*)g)[t], bb = ((const float2*)be)[t];
    float sx = dx * rs * gg.x + bb.x, sy = dy * rs * gg.y + bb.y;
    if (samples[n] < 0) { sx = 0.f; sy = 0.f; }
    float2 xx = ((const float2*)(x + (size_t)n * DIM))[t];
    float ox = xx.x + sx, oy = xx.y + sy;
    ((float2*)(dec + (size_t)n * DIM))[t] = make_float2(ox, oy);
    decb[(size_t)n * 256 + t] = (unsigned)f2bf(ox) | ((unsigned)f2bf(oy) << 16);
}

// ---------------------------------------------------------------- launcher
extern "C" void kernel_launch(void* const* d_in, const int* in_sizes, int n_in,
                              void* d_out, int out_size, void* d_ws, size_t ws_size,
                              hipStream_t stream)
{
    const float* dec_output = (const float*)d_in[0];
    const float* mem_attn   = (const float*)d_in[1];
    const float* enc_mem    = (const float*)d_in[2];
    const float* temb_mem   = (const float*)d_in[3];
    const int*   mask_mem   = (const int*)d_in[4];
    const float* g0  = (const float*)d_in[6];
    const float* be0 = (const float*)d_in[7];
    const float* g1  = (const float*)d_in[8];
    const float* be1 = (const float*)d_in[9];
    const float* Wq  = (const float*)d_in[10];
    const float* bq  = (const float*)d_in[11];
    const float* Wk  = (const float*)d_in[12];
    const float* bk  = (const float*)d_in[13];
    const float* Wv  = (const float*)d_in[14];
    const float* bv  = (const float*)d_in[15];
    const float* Wo  = (const float*)d_in[16];
    const float* bo  = (const float*)d_in[17];
    const float* f1W1 = (const float*)d_in[18];
    const float* f1b1 = (const float*)d_in[19];
    const float* f1W2 = (const float*)d_in[20];
    const float* f1b2 = (const float*)d_in[21];
    const float* f2W1 = (const float*)d_in[22];
    const float* f2b1 = (const float*)d_in[23];
    const float* f2W2 = (const float*)d_in[24];
    const float* f2b2 = (const float*)d_in[25];
    float* out = (float*)d_out;

    float* ws = (float*)d_ws;
    float*          x_f   = ws + 0;                    // 524288
    unsigned*       x_b   = (unsigned*)(ws + 524288);  // 262144 f (dead after QH GEMM)
    float*          qh_f  = ws + 786432;               // 524288
    unsigned short* qh_b  = (unsigned short*)(ws + 1310720); // 262144 f
    unsigned short* u_b   = (unsigned short*)(ws + 1572864); // 2097152 f
    unsigned short* a_b   = (unsigned short*)(ws + 3670016); // 2097152 f
    unsigned short* wqt   = (unsigned short*)(ws + 5767168);
    unsigned short* wkc   = (unsigned short*)(ws + 5898240);
    unsigned short* wvt   = (unsigned short*)(ws + 6029312);
    unsigned short* wot   = (unsigned short*)(ws + 6160384);
    unsigned short* f1w1t = (unsigned short*)(ws + 6291456);
    unsigned short* f1w2t = (unsigned short*)(ws + 6815744);
    unsigned short* f2w1t = (unsigned short*)(ws + 7340032);
    unsigned short* f2w2t = (unsigned short*)(ws + 7864320);
    int*            smp   = (int*)(ws + 8388608);
    // P aliases x_b (x_b's last reader is the QH GEMM, before attn_scores)
    unsigned short* p_b   = (unsigned short*)x_b;      // 1024*512 bf16 = 1 MB
    // aliases inside u_b region (dead after attn_scores):
    float*          st0_f = (float*)u_b + 0;
    unsigned short* st0_b = (unsigned short*)((float*)u_b + 524288);
    float*          t1_f  = (float*)u_b + 786432;
    float*          dec_f = (float*)u_b + 1310720;
    unsigned*       dec_b = (unsigned*)((float*)u_b + 1835008);
    // aliases inside a_b region (dead after CTX GEMM):
    unsigned short* h1_b  = a_b;
    unsigned short* h2_b  = (unsigned short*)((float*)a_b + 1048576);

    PrepPtrs pp;
    pp.src[0] = Wq;   pp.dst[0] = wqt;
    pp.src[1] = Wk;   pp.dst[1] = wkc;
    pp.src[2] = Wv;   pp.dst[2] = wvt;
    pp.src[3] = Wo;   pp.dst[3] = wot;
    pp.src[4] = f1W1; pp.dst[4] = f1w1t;
    pp.src[5] = f1W2; pp.dst[5] = f1w2t;
    pp.src[6] = f2W1; pp.dst[6] = f2w1t;
    pp.src[7] = f2W2; pp.dst[7] = f2w2t;
    prep_weights_k<<<5120, 256, 0, stream>>>(pp);
    ln0_argmax_k<<<NQ, 256, 0, stream>>>(dec_output, mem_attn, g0, be0, x_f, x_b, smp);
    // QH = X @ Wq + bq
    mfma_gemm<false, true, false, true, true><<<dim3(8, 16, 1), 256, 0, stream>>>(
        (const unsigned short*)x_b, wqt, qh_f, qh_b, bq, nullptr,
        DIM, DIM, DIM, DIM, 0, 0, 0, 0);
    // U_h = QH_h @ Wk_h^T (batched heads, K=64)
    mfma_gemm<false, false, false, false, true><<<dim3(8, 16, NH), 256, 0, stream>>>(
        qh_b, wkc, nullptr, u_b, nullptr, nullptr,
        DHD, DIM, DIM, NH * DIM, DHD, DHD, DIM, 0);
    // scores -> softmax -> P
    attn_scores_k<<<NQ, 256, 0, stream>>>(qh_f, u_b, enc_mem, mask_mem, smp, bk, p_b);
    // PV -> a (bf16)
    attn_pv_k<<<dim3(NQ, 2), 256, 0, stream>>>(p_b, temb_mem, smp, (unsigned*)a_b);
    // CTX_h = A_h @ Wv_h + bv_h
    mfma_gemm<false, true, false, false, true><<<dim3(1, 16, NH), 256, 0, stream>>>(
        a_b, wvt, nullptr, qh_b, bv, nullptr,
        DIM, NH * DIM, DIM, DIM, DIM, DHD * DIM, DHD, DHD);
    // ST0 = X + CTX @ Wo + bo
    mfma_gemm<false, true, true, true, true><<<dim3(8, 16, 1), 256, 0, stream>>>(
        qh_b, wot, st0_f, st0_b, bo, x_f, DIM, DIM, DIM, DIM, 0, 0, 0, 0);
    // H1 = relu(ST0 @ f1W1 + f1b1)  [128x128 tile]
    mfma_gemm128<true><<<dim3(16, 8), 256, 0, stream>>>(
        st0_b, f1w1t, h1_b, f1b1, DIM, DIM, DIM, DFF);
    // T1 = ST0 + H1 @ f1W2 + f1b2
    mfma_gemm<false, true, true, true, false><<<dim3(8, 16, 1), 256, 0, stream>>>(
        h1_b, f1w2t, t1_f, nullptr, f1b2, st0_f, DFF, DFF, DFF, DIM, 0, 0, 0, 0);
    // DEC = X + mask * LN1(T1)
    ln1_mask_add_k<<<NQ, 256, 0, stream>>>(t1_f, g1, be1, smp, x_f, dec_f, dec_b);
    // H2 = relu(DEC @ f2W1 + f2b1)  [128x128 tile]
    mfma_gemm128<true><<<dim3(16, 8), 256, 0, stream>>>(
        (const unsigned short*)dec_b, f2w1t, h2_b, f2b1, DIM, DIM, DIM, DFF);
    // OUT = DEC + H2 @ f2W2 + f2b2
    mfma_gemm<false, true, true, true, false><<<dim3(8, 16, 1), 256, 0, stream>>>(
        h2_b, f2w2t, out, nullptr, f2b2, dec_f, DFF, DFF, DFF, DIM, 0, 0, 0, 0);

    (void)in_sizes; (void)n_in; (void)out_size; (void)ws_size;
}

// Round 5
// 157.220 us; speedup vs baseline: 1.0987x; 1.0987x over previous
//
#include <hip/hip_runtime.h>
#include <math.h>

// Problem constants (fixed by the reference)
#define NQ   1024      // B*LT
#define DIM  512
#define NH   8
#define DHD  64
#define DFF  2048
#define LM   64        // LMEM

typedef __bf16 bf16x8 __attribute__((ext_vector_type(8)));
typedef float  f32x4  __attribute__((ext_vector_type(4)));

__device__ __forceinline__ unsigned short f2bf(float f) {
    unsigned u = __builtin_bit_cast(unsigned, f);
    return (unsigned short)((u + 0x7fffu + ((u >> 16) & 1u)) >> 16);
}
__device__ __forceinline__ float bflo(unsigned p) {
    return __builtin_bit_cast(float, p << 16);
}
__device__ __forceinline__ float bfhi(unsigned p) {
    return __builtin_bit_cast(float, p & 0xffff0000u);
}

__device__ __forceinline__ void gload16(const void* g, void* l) {
    __builtin_amdgcn_global_load_lds(
        (const __attribute__((address_space(1))) unsigned*)g,
        (__attribute__((address_space(3))) unsigned*)l, 16, 0, 0);
}

// ---------------------------------------------------------------- helpers
__device__ __forceinline__ float blk_sum(float v, volatile float* red) {
#pragma unroll
    for (int o = 32; o; o >>= 1) v += __shfl_down(v, o);
    __syncthreads();
    if ((threadIdx.x & 63) == 0) red[threadIdx.x >> 6] = v;
    __syncthreads();
    return red[0] + red[1] + red[2] + red[3];
}

// ------------------------------------------------- K1: weight-prep + LN0 + argmax
struct PrepPtrs {
    const float* src[8];
    unsigned short* dst[8];
};
// blocks [0,5120): weight prep; blocks [5120,6144): LN0+argmax for n = bid-5120
__global__ __launch_bounds__(256) void prep_ln0_k(
    PrepPtrs p,
    const float* __restrict__ dec_out, const float* __restrict__ attn_out,
    const float* __restrict__ g, const float* __restrict__ be,
    float* __restrict__ x, unsigned* __restrict__ xb, int* __restrict__ samples)
{
    __shared__ float tile[32][33];
    __shared__ float red[4];
    __shared__ float rv[4]; __shared__ int ri[4];
    const int bid = blockIdx.x;

    if (bid < 5120) {
        int m, lt;
        if (bid < 1024) { m = bid >> 8; lt = bid & 255; }
        else { m = 4 + ((bid - 1024) >> 10); lt = (bid - 1024) & 1023; }
        const int RS = (m < 4) ? 512 : ((m == 5 || m == 7) ? 2048 : 512);
        const int CS = (m < 4) ? 512 : ((m == 5 || m == 7) ? 512 : 2048);
        const int TC = CS >> 5;
        const int tr = lt / TC, tc = lt % TC;
        const float* s = p.src[m];
        unsigned short* d = p.dst[m];
        const int tx = threadIdx.x & 31, ty = threadIdx.x >> 5;
        if (m == 1) {
#pragma unroll
            for (int i = 0; i < 32; i += 8) {
                size_t idx = (size_t)(tr * 32 + ty + i) * CS + tc * 32 + tx;
                d[idx] = f2bf(s[idx]);
            }
        } else {
#pragma unroll
            for (int i = 0; i < 32; i += 8)
                tile[ty + i][tx] = s[(size_t)(tr * 32 + ty + i) * CS + tc * 32 + tx];
            __syncthreads();
#pragma unroll
            for (int i = 0; i < 32; i += 8)
                d[(size_t)(tc * 32 + ty + i) * RS + tr * 32 + tx] = f2bf(tile[tx][ty + i]);
        }
        return;
    }

    const int n = bid - 5120, t = threadIdx.x;
    float2 v = ((const float2*)(dec_out + (size_t)n * DIM))[t];
    float mu  = blk_sum(v.x + v.y, red) * (1.f / DIM);
    float dx = v.x - mu, dy = v.y - mu;
    float var = blk_sum(dx * dx + dy * dy, red) * (1.f / DIM);
    float rs = rsqrtf(var + 1e-5f);
    float2 gg = ((const float2*)g)[t], bb = ((const float2*)be)[t];
    float ox = dx * rs * gg.x + bb.x, oy = dy * rs * gg.y + bb.y;
    ((float2*)(x + (size_t)n * DIM))[t] = make_float2(ox, oy);
    xb[(size_t)n * 256 + t] = (unsigned)f2bf(ox) | ((unsigned)f2bf(oy) << 16);

    const float* ar = attn_out + (size_t)n * 1025;
    float bv = -INFINITY; int bi = 0x7fffffff;
    for (int i = t; i < 1025; i += 256) {
        float val = ar[i];
        if (val > bv || (val == bv && i < bi)) { bv = val; bi = i; }
    }
#pragma unroll
    for (int o = 32; o; o >>= 1) {
        float ov = __shfl_down(bv, o); int oi = __shfl_down(bi, o);
        if (ov > bv || (ov == bv && oi < bi)) { bv = ov; bi = oi; }
    }
    if ((t & 63) == 0) { rv[t >> 6] = bv; ri[t >> 6] = bi; }
    __syncthreads();
    if (t == 0) {
#pragma unroll
        for (int w = 1; w < 4; ++w)
            if (rv[w] > bv || (rv[w] == bv && ri[w] < bi)) { bv = rv[w]; bi = ri[w]; }
        samples[n] = bi - 1;
    }
}

// ------------------------------------------------- bf16 MFMA GEMM, 64x64 tile
template<bool RELU, bool BIAS, bool RES, bool WF32, bool WBF>
__global__ __launch_bounds__(256) void mfma_gemm(
    const unsigned short* __restrict__ A, const unsigned short* __restrict__ Bt,
    float* __restrict__ Cf, unsigned short* __restrict__ Cb,
    const float* __restrict__ bias, const float* __restrict__ res,
    int K, int lda, int ldb, int ldc,
    int sA, int sB, int sC, int sBias)
{
    __shared__ unsigned short Ab[2][64 * 64];
    __shared__ unsigned short Bb[2][64 * 64];
    const int t = threadIdx.x, lane = t & 63, wid = t >> 6;
    const int bm = blockIdx.y * 64, bn = blockIdx.x * 64, bz = blockIdx.z;
    const unsigned short* Abase = A + (size_t)bz * sA + (size_t)bm * lda;
    const unsigned short* Bbase = Bt + (size_t)bz * sB + (size_t)bn * ldb;

    const int r0 = wid * 16 + (lane >> 3);
    const int cbs = lane & 7;

#define STAGE_T(buf, base, ld, kt)                                              \
    {                                                                           \
        int r_ = r0;                                                            \
        gload16(base + (size_t)r_ * ld + (kt) * 64 + ((cbs ^ (r_ & 7)) << 3),   \
                &buf[(wid * 2 + 0) * 512]);                                     \
        r_ = r0 + 8;                                                            \
        gload16(base + (size_t)r_ * ld + (kt) * 64 + ((cbs ^ (r_ & 7)) << 3),   \
                &buf[(wid * 2 + 1) * 512]);                                     \
    }

    const int lr = lane & 15, lg = lane >> 4;
    const int wr = (wid >> 1) * 32, wc = (wid & 1) * 32;
    const int mA0 = wr + lr, mA1 = wr + 16 + lr;
    const int nB0 = wc + lr, nB1 = wc + 16 + lr;
    f32x4 acc[2][2] = {};

#define COMPUTE(b)                                                              \
    _Pragma("unroll")                                                           \
    for (int kk = 0; kk < 2; ++kk) {                                            \
        const int kb = kk * 4 + lg;                                             \
        bf16x8 a0 = *(const bf16x8*)&Ab[b][mA0 * 64 + ((kb ^ (mA0 & 7)) << 3)]; \
        bf16x8 a1 = *(const bf16x8*)&Ab[b][mA1 * 64 + ((kb ^ (mA1 & 7)) << 3)]; \
        bf16x8 b0 = *(const bf16x8*)&Bb[b][nB0 * 64 + ((kb ^ (nB0 & 7)) << 3)]; \
        bf16x8 b1 = *(const bf16x8*)&Bb[b][nB1 * 64 + ((kb ^ (nB1 & 7)) << 3)]; \
        acc[0][0] = __builtin_amdgcn_mfma_f32_16x16x32_bf16(a0, b0, acc[0][0], 0, 0, 0); \
        acc[0][1] = __builtin_amdgcn_mfma_f32_16x16x32_bf16(a0, b1, acc[0][1], 0, 0, 0); \
        acc[1][0] = __builtin_amdgcn_mfma_f32_16x16x32_bf16(a1, b0, acc[1][0], 0, 0, 0); \
        acc[1][1] = __builtin_amdgcn_mfma_f32_16x16x32_bf16(a1, b1, acc[1][1], 0, 0, 0); \
    }

    STAGE_T(Ab[0], Abase, lda, 0);
    STAGE_T(Bb[0], Bbase, ldb, 0);
    __syncthreads();
    const int NT = K >> 6;
    int cur = 0;
    for (int kt = 0; kt < NT; ++kt) {
        if (kt + 1 < NT) {
            STAGE_T(Ab[cur ^ 1], Abase, lda, kt + 1);
            STAGE_T(Bb[cur ^ 1], Bbase, ldb, kt + 1);
        }
        if (cur == 0) { COMPUTE(0); } else { COMPUTE(1); }
        __syncthreads();
        cur ^= 1;
    }

#pragma unroll
    for (int fm = 0; fm < 2; ++fm)
#pragma unroll
    for (int fn = 0; fn < 2; ++fn) {
        const int col = bn + wc + fn * 16 + lr;
        float bia = BIAS ? bias[bz * sBias + col] : 0.f;
#pragma unroll
        for (int r = 0; r < 4; ++r) {
            const int row = bm + wr + fm * 16 + lg * 4 + r;
            const size_t ci = (size_t)bz * sC + (size_t)row * ldc + col;
            float v = acc[fm][fn][r] + bia;
            if (RES) v += res[(size_t)row * ldc + col];
            if (RELU) v = fmaxf(v, 0.f);
            if (WF32) Cf[ci] = v;
            if (WBF)  Cb[ci] = f2bf(v);
        }
    }
#undef STAGE_T
#undef COMPUTE
}

// ------------------------------------------------- K4: partial scores via MFMA
// block (n, half): S_part[n][half][h][k] = enc[s,k, half*256..+256]·u[n,h,same]
//                  (+ qh·bk_h folded into half 0)
__global__ __launch_bounds__(256) void attn_scores_k(
    const float* __restrict__ qh, const unsigned short* __restrict__ u_bf,
    const float* __restrict__ enc, const int* __restrict__ samples,
    const float* __restrict__ bk, float* __restrict__ s_part)
{
    __shared__ float Cs_lds[8];
    const int n = blockIdx.x, half = blockIdx.y, t = threadIdx.x;
    const int lane = t & 63, w = t >> 6;
    int s = samples[n]; if (s < 0) s = 0;

    const float4* kb = (const float4*)(enc + (size_t)s * (LM * DIM));
    const int key = w * 16 + (lane & 15);
    const int lg = lane >> 4;
    const int h = lane & 15;
    const int base = key * 128 + half * 64 + lg * 2;   // float4 units
    float4 pf[4][2];
#pragma unroll
    for (int ss = 0; ss < 4; ++ss) {
        pf[ss][0] = kb[base + ss * 8];
        pf[ss][1] = kb[base + ss * 8 + 1];
    }

    if (w == 1) {
        int hq = lane >> 3, j = lane & 7;
        const float4* q4 = (const float4*)(qh + (size_t)n * DIM + hq * 64 + j * 8);
        const float4* b4 = (const float4*)(bk + hq * 64 + j * 8);
        float4 qa = q4[0], qb = q4[1], ba = b4[0], bb = b4[1];
        float c = qa.x * ba.x + qa.y * ba.y + qa.z * ba.z + qa.w * ba.w
                + qb.x * bb.x + qb.y * bb.y + qb.z * bb.z + qb.w * bb.w;
        c += __shfl_xor(c, 1); c += __shfl_xor(c, 2); c += __shfl_xor(c, 4);
        if (j == 0) Cs_lds[hq] = c;
    }

    const unsigned short* ub = u_bf + (size_t)n * 4096 + (size_t)(h & 7) * 512 + half * 256;
    f32x4 acc = {};
#pragma unroll
    for (int step = 0; step < 8; ++step) {
        float4 a0 = pf[step & 3][0], a1 = pf[step & 3][1];
        if (step + 4 < 8) {
            pf[step & 3][0] = kb[base + (step + 4) * 8];
            pf[step & 3][1] = kb[base + (step + 4) * 8 + 1];
        }
        bf16x8 af;
        af[0] = (__bf16)a0.x; af[1] = (__bf16)a0.y;
        af[2] = (__bf16)a0.z; af[3] = (__bf16)a0.w;
        af[4] = (__bf16)a1.x; af[5] = (__bf16)a1.y;
        af[6] = (__bf16)a1.z; af[7] = (__bf16)a1.w;
        bf16x8 bfr = *(const bf16x8*)&ub[(step * 4 + lg) * 8];
        acc = __builtin_amdgcn_mfma_f32_16x16x32_bf16(af, bfr, acc, 0, 0, 0);
    }
    __syncthreads();
    if (h < 8) {
        float cs = (half == 0) ? Cs_lds[h] : 0.f;
        float* sp = s_part + (((size_t)n * 2 + half) * 8 + h) * 64 + w * 16 + lg * 4;
        *(float4*)sp = make_float4(acc[0] + cs, acc[1] + cs, acc[2] + cs, acc[3] + cs);
    }
}

// ------------------------------------------------- K5: softmax + PV (d-halved)
__global__ __launch_bounds__(256) void attn_pv_k(
    const float* __restrict__ s_part, const float* __restrict__ vemb,
    const int* __restrict__ maskmem, const int* __restrict__ samples,
    unsigned* __restrict__ a_bf)
{
    __shared__ float Sp_lds[1024];
    __shared__ uint4 P_lds[64];
    __shared__ float2 Red[8][128];
    __shared__ int Msk_lds[64];
    const int n = blockIdx.x, dh = blockIdx.y, t = threadIdx.x;
    const int lane = t & 63, w = t >> 6;
    int s = samples[n]; if (s < 0) s = 0;

    ((float4*)Sp_lds)[t] = ((const float4*)(s_part + (size_t)n * 1024))[t];
    if (t < 64) Msk_lds[t] = maskmem[(size_t)s * LM + t];
    __syncthreads();

    // softmax: wave w handles heads w and w+4 (key = lane)
#pragma unroll
    for (int hh = 0; hh < 2; ++hh) {
        const int h = w + hh * 4;
        float sc = (Sp_lds[h * 64 + lane] + Sp_lds[512 + h * 64 + lane]) * 0.125f;
        sc = (Msk_lds[lane] != 0) ? sc : -1e9f;
        float m = sc;
#pragma unroll
        for (int o = 32; o; o >>= 1) m = fmaxf(m, __shfl_xor(m, o));
        float e = __expf(sc - m);
        float su = e;
#pragma unroll
        for (int o = 32; o; o >>= 1) su += __shfl_xor(su, o);
        ((unsigned short*)P_lds)[lane * 8 + h] = f2bf(e / su);
    }
    __syncthreads();

    const int c = t & 127, kh = t >> 7;
    const float2* vb = (const float2*)(vemb + (size_t)s * (LM * DIM)) + dh * 128 + c;
    float2 acc8[8];
#pragma unroll
    for (int hh = 0; hh < 8; ++hh) acc8[hh] = make_float2(0.f, 0.f);
#pragma unroll 8
    for (int i = 0; i < 32; ++i) {
        const int k = kh * 32 + i;
        float2 v = vb[(size_t)k * 256];
        uint4 pr = P_lds[k];
        float p0 = bflo(pr.x), p1 = bfhi(pr.x);
        float p2 = bflo(pr.y), p3 = bfhi(pr.y);
        float p4 = bflo(pr.z), p5 = bfhi(pr.z);
        float p6 = bflo(pr.w), p7 = bfhi(pr.w);
        acc8[0].x = fmaf(p0, v.x, acc8[0].x); acc8[0].y = fmaf(p0, v.y, acc8[0].y);
        acc8[1].x = fmaf(p1, v.x, acc8[1].x); acc8[1].y = fmaf(p1, v.y, acc8[1].y);
        acc8[2].x = fmaf(p2, v.x, acc8[2].x); acc8[2].y = fmaf(p2, v.y, acc8[2].y);
        acc8[3].x = fmaf(p3, v.x, acc8[3].x); acc8[3].y = fmaf(p3, v.y, acc8[3].y);
        acc8[4].x = fmaf(p4, v.x, acc8[4].x); acc8[4].y = fmaf(p4, v.y, acc8[4].y);
        acc8[5].x = fmaf(p5, v.x, acc8[5].x); acc8[5].y = fmaf(p5, v.y, acc8[5].y);
        acc8[6].x = fmaf(p6, v.x, acc8[6].x); acc8[6].y = fmaf(p6, v.y, acc8[6].y);
        acc8[7].x = fmaf(p7, v.x, acc8[7].x); acc8[7].y = fmaf(p7, v.y, acc8[7].y);
    }
    if (kh == 1) {
#pragma unroll
        for (int hh = 0; hh < 8; ++hh) Red[hh][c] = acc8[hh];
    }
    __syncthreads();
    if (kh == 0) {
        unsigned* an = a_bf + (size_t)n * 2048 + dh * 128;
#pragma unroll
        for (int hh = 0; hh < 8; ++hh) {
            float2 r = Red[hh][c];
            float ox = acc8[hh].x + r.x, oy = acc8[hh].y + r.y;
            an[hh * 256 + c] = (unsigned)f2bf(ox) | ((unsigned)f2bf(oy) << 16);
        }
    }
}

// ------------------------------------------------- K10: combine T1 parts + LN + mask + x
__global__ __launch_bounds__(256) void ln1_mask_add_k(
    const float* __restrict__ t1p, const float* __restrict__ st0,
    const float* __restrict__ b2, const float* __restrict__ g,
    const float* __restrict__ be, const int* __restrict__ samples,
    const float* __restrict__ x, float* __restrict__ dec, unsigned* __restrict__ decb)
{
    __shared__ float red[4];
    const int n = blockIdx.x, t = threadIdx.x;
    float2 p0 = ((const float2*)(t1p + (size_t)n * DIM))[t];
    float2 p1 = ((const float2*)(t1p + (size_t)(NQ + n) * DIM))[t];
    float2 s0 = ((const float2*)(st0 + (size_t)n * DIM))[t];
    float2 b2v = ((const float2*)b2)[t];
    float2 v = make_float2(p0.x + p1.x + s0.x + b2v.x, p0.y + p1.y + s0.y + b2v.y);
    float mu  = blk_sum(v.x + v.y, red) * (1.f / DIM);
    float dx = v.x - mu, dy = v.y - mu;
    float var = blk_sum(dx * dx + dy * dy, red) * (1.f / DIM);
    float rs = rsqrtf(var + 1e-5f);
    float2 gg = ((const float2*)g)[t], bb = ((const float2*)be)[t];
    float sx = dx * rs * gg.x + bb.x, sy = dy * rs * gg.y + bb.y;
    if (samples[n] < 0) { sx = 0.f; sy = 0.f; }
    float2 xx = ((const float2*)(x + (size_t)n * DIM))[t];
    float ox = xx.x + sx, oy = xx.y + sy;
    ((float2*)(dec + (size_t)n * DIM))[t] = make_float2(ox, oy);
    decb[(size_t)n * 256 + t] = (unsigned)f2bf(ox) | ((unsigned)f2bf(oy) << 16);
}

// ---------------------------------------------------------------- launcher
extern "C" void kernel_launch(void* const* d_in, const int* in_sizes, int n_in,
                              void* d_out, int out_size, void* d_ws, size_t ws_size,
                              hipStream_t stream)
{
    const float* dec_output = (const float*)d_in[0];
    const float* mem_attn   = (const float*)d_in[1];
    const float* enc_mem    = (const float*)d_in[2];
    const float* temb_mem   = (const float*)d_in[3];
    const int*   mask_mem   = (const int*)d_in[4];
    const float* g0  = (const float*)d_in[6];
    const float* be0 = (const float*)d_in[7];
    const float* g1  = (const float*)d_in[8];
    const float* be1 = (const float*)d_in[9];
    const float* Wq  = (const float*)d_in[10];
    const float* bq  = (const float*)d_in[11];
    const float* Wk  = (const float*)d_in[12];
    const float* bk  = (const float*)d_in[13];
    const float* Wv  = (const float*)d_in[14];
    const float* bv  = (const float*)d_in[15];
    const float* Wo  = (const float*)d_in[16];
    const float* bo  = (const float*)d_in[17];
    const float* f1W1 = (const float*)d_in[18];
    const float* f1b1 = (const float*)d_in[19];
    const float* f1W2 = (const float*)d_in[20];
    const float* f1b2 = (const float*)d_in[21];
    const float* f2W1 = (const float*)d_in[22];
    const float* f2b1 = (const float*)d_in[23];
    const float* f2W2 = (const float*)d_in[24];
    const float* f2b2 = (const float*)d_in[25];
    float* out = (float*)d_out;

    float* ws = (float*)d_ws;
    float*          x_f   = ws + 0;                    // 524288
    unsigned*       x_b   = (unsigned*)(ws + 524288);  // 262144 f
    float*          qh_f  = ws + 786432;               // 524288
    unsigned short* qh_b  = (unsigned short*)(ws + 1310720); // 262144 f
    unsigned short* u_b   = (unsigned short*)(ws + 1572864); // 2097152 f
    unsigned short* a_b   = (unsigned short*)(ws + 3670016); // 2097152 f
    unsigned short* wqt   = (unsigned short*)(ws + 5767168);
    unsigned short* wkc   = (unsigned short*)(ws + 5898240);
    unsigned short* wvt   = (unsigned short*)(ws + 6029312);
    unsigned short* wot   = (unsigned short*)(ws + 6160384);
    unsigned short* f1w1t = (unsigned short*)(ws + 6291456);
    unsigned short* f1w2t = (unsigned short*)(ws + 6815744);
    unsigned short* f2w1t = (unsigned short*)(ws + 7340032);
    unsigned short* f2w2t = (unsigned short*)(ws + 7864320);
    int*            smp   = (int*)(ws + 8388608);      // 1024 ints
    float*          s_prt = ws + 8392704;              // 1048576 f (4 MB)
    float*          t1p_f = ws + 9441280;              // 1048576 f (two 1024x512 parts)
    // aliases inside u_b region (dead after attn_scores):
    float*          st0_f = (float*)u_b + 0;
    unsigned short* st0_b = (unsigned short*)((float*)u_b + 524288);
    float*          dec_f = (float*)u_b + 1310720;
    unsigned*       dec_b = (unsigned*)((float*)u_b + 1835008);
    // aliases inside a_b region (dead after CTX GEMM):
    unsigned short* h1_b  = a_b;
    unsigned short* h2_b  = (unsigned short*)((float*)a_b + 1048576);

    PrepPtrs pp;
    pp.src[0] = Wq;   pp.dst[0] = wqt;
    pp.src[1] = Wk;   pp.dst[1] = wkc;
    pp.src[2] = Wv;   pp.dst[2] = wvt;
    pp.src[3] = Wo;   pp.dst[3] = wot;
    pp.src[4] = f1W1; pp.dst[4] = f1w1t;
    pp.src[5] = f1W2; pp.dst[5] = f1w2t;
    pp.src[6] = f2W1; pp.dst[6] = f2w1t;
    pp.src[7] = f2W2; pp.dst[7] = f2w2t;
    // 1. weight prep + LN0 + argmax (one launch)
    prep_ln0_k<<<5120 + NQ, 256, 0, stream>>>(pp, dec_output, mem_attn, g0, be0,
                                              x_f, x_b, smp);
    // 2. QH = X @ Wq + bq
    mfma_gemm<false, true, false, true, true><<<dim3(8, 16, 1), 256, 0, stream>>>(
        (const unsigned short*)x_b, wqt, qh_f, qh_b, bq, nullptr,
        DIM, DIM, DIM, DIM, 0, 0, 0, 0);
    // 3. U_h = QH_h @ Wk_h^T (batched heads, K=64)
    mfma_gemm<false, false, false, false, true><<<dim3(8, 16, NH), 256, 0, stream>>>(
        qh_b, wkc, nullptr, u_b, nullptr, nullptr,
        DHD, DIM, DIM, NH * DIM, DHD, DHD, DIM, 0);
    // 4. partial scores (split-K over 2 blocks/query)
    attn_scores_k<<<dim3(NQ, 2), 256, 0, stream>>>(qh_f, u_b, enc_mem, smp, bk, s_prt);
    // 5. softmax + PV -> a (bf16)
    attn_pv_k<<<dim3(NQ, 2), 256, 0, stream>>>(s_prt, temb_mem, mask_mem, smp,
                                               (unsigned*)a_b);
    // 6. CTX_h = A_h @ Wv_h + bv_h
    mfma_gemm<false, true, false, false, true><<<dim3(1, 16, NH), 256, 0, stream>>>(
        a_b, wvt, nullptr, qh_b, bv, nullptr,
        DIM, NH * DIM, DIM, DIM, DIM, DHD * DIM, DHD, DHD);
    // 7. ST0 = X + CTX @ Wo + bo
    mfma_gemm<false, true, true, true, true><<<dim3(8, 16, 1), 256, 0, stream>>>(
        qh_b, wot, st0_f, st0_b, bo, x_f, DIM, DIM, DIM, DIM, 0, 0, 0, 0);
    // 8. H1 = relu(ST0 @ f1W1 + f1b1)  [64² tile, 512 blocks]
    mfma_gemm<true, true, false, false, true><<<dim3(32, 16, 1), 256, 0, stream>>>(
        st0_b, f1w1t, nullptr, h1_b, f1b1, nullptr, DIM, DIM, DIM, DFF, 0, 0, 0, 0);
    // 9. T1 parts = H1 @ f1W2 (split-K=2, no bias/res; combined in LN1)
    mfma_gemm<false, false, false, true, false><<<dim3(8, 16, 2), 256, 0, stream>>>(
        h1_b, f1w2t, t1p_f, nullptr, nullptr, nullptr,
        1024, DFF, DFF, DIM, 1024, 1024, NQ * DIM, 0);
    // 10. DEC = X + mask * LN1(p0 + p1 + ST0 + f1b2)
    ln1_mask_add_k<<<NQ, 256, 0, stream>>>(t1p_f, st0_f, f1b2, g1, be1, smp,
                                           x_f, dec_f, dec_b);
    // 11. H2 = relu(DEC @ f2W1 + f2b1)  [64² tile, 512 blocks]
    mfma_gemm<true, true, false, false, true><<<dim3(32, 16, 1), 256, 0, stream>>>(
        (const unsigned short*)dec_b, f2w1t, nullptr, h2_b, f2b1, nullptr,
        DIM, DIM, DIM, DFF, 0, 0, 0, 0);
    // 12. OUT = DEC + H2 @ f2W2 + f2b2
    mfma_gemm<false, true, true, true, false><<<dim3(8, 16, 1), 256, 0, stream>>>(
        h2_b, f2w2t, out, nullptr, f2b2, dec_f, DFF, DFF, DFF, DIM, 0, 0, 0, 0);

    (void)in_sizes; (void)n_in; (void)out_size; (void)ws_size;
}